// Round 1
// 6293.468 us; speedup vs baseline: 1.2170x; 1.2170x over previous
//
#include <hip/hip_runtime.h>

// ---------------- problem constants ----------------
#define NN 100000     // nodes
#define NE 800000     // edges
#define DIN 256
#define DHID 256
#define DOUT 128
#define DEP 256
#define NCLS 40

static constexpr size_t OFF_EF = (size_t)NN * DOUT;                 // edge_feats
static constexpr size_t OFF_LG = OFF_EF + (size_t)NE * DOUT;        // logits
static constexpr size_t OFF_EI = OFF_LG + (size_t)NN * NCLS;        // edge_index (as float)

// ---------------- utility kernels ----------------

// Detect int64 vs int32 edge_index layout and convert to int32 buffer.
__global__ __launch_bounds__(256) void convert_ei_kernel(const int* __restrict__ ei32,
                                                         int* __restrict__ eidx, int n2e) {
    __shared__ int is64;
    if (threadIdx.x == 0) {
        int ored = 0;
        for (int i = 0; i < 64; ++i) ored |= ei32[2 * i + 1];
        is64 = (ored == 0) ? 1 : 0;   // int64 little-endian: high words all zero
    }
    __syncthreads();
    int i = blockIdx.x * 256 + threadIdx.x;
    if (i < n2e) {
        if (is64) {
            const long long* e64 = (const long long*)ei32;
            eidx[i] = (int)e64[i];
        } else {
            eidx[i] = ei32[i];
        }
    }
}

__global__ __launch_bounds__(256) void zero_kernel(float4* __restrict__ p, int n4) {
    int i = blockIdx.x * 256 + threadIdx.x;
    if (i < n4) p[i] = make_float4(0.f, 0.f, 0.f, 0.f);
}

__global__ __launch_bounds__(256) void degree_kernel(const int* __restrict__ eidx,
                                                     float* __restrict__ deg) {
    int e = blockIdx.x * 256 + threadIdx.x;
    if (e < NE) atomicAdd(&deg[eidx[NE + e]], 1.0f);
}

__global__ __launch_bounds__(256) void dinv_kernel(const float* __restrict__ deg,
                                                   float* __restrict__ dinv) {
    int v = blockIdx.x * 256 + threadIdx.x;
    if (v < NN) dinv[v] = rsqrtf(deg[v] + 1.0f);   // +1 self-loop; deg>=1 always
}

__global__ __launch_bounds__(256) void copyei_kernel(const int* __restrict__ eidx,
                                                     float* __restrict__ out, int n2e) {
    int i = blockIdx.x * 256 + threadIdx.x;
    if (i < n2e) out[i] = (float)eidx[i];
}

// ---------------- generic 32-row GEMM: C[M,N] = A[M,K] @ B[K,N] (+bias) ----------------
// 256 threads, TM=32 rows/block. K,N <= 256. JPT cols per thread.
template <int K, int N, int JPT, bool BIAS, int PAD>
__global__ __launch_bounds__(256) void gemm32_kernel(const float* __restrict__ A,
                                                     const float* __restrict__ B,
                                                     const float* __restrict__ bias,
                                                     float* __restrict__ C) {
    constexpr int TPR = N / JPT;       // threads covering one row's N cols
    constexpr int GROUPS = 256 / TPR;  // row groups
    constexpr int RPT = 32 / GROUPS;   // rows per thread
    __shared__ float As[32][K + PAD];

    const int t = threadIdx.x;
    const size_t m0 = (size_t)blockIdx.x * 32;

    // stage A tile (M is an exact multiple of 32 for all uses)
    for (int idx4 = t; idx4 < 32 * K / 4; idx4 += 256) {
        int idx = idx4 * 4;
        int r = idx / K, cc = idx % K;
        float4 v = *reinterpret_cast<const float4*>(A + (m0 + r) * K + cc);
        As[r][cc + 0] = v.x; As[r][cc + 1] = v.y;
        As[r][cc + 2] = v.z; As[r][cc + 3] = v.w;
    }
    __syncthreads();

    const int g = t / TPR;
    const int jbase = (t % TPR) * JPT;

    float acc[RPT][JPT];
#pragma unroll
    for (int i = 0; i < RPT; ++i)
#pragma unroll
        for (int j = 0; j < JPT; ++j) acc[i][j] = 0.f;

    if constexpr ((JPT % 4) == 0 && PAD == 0) {
        for (int k0 = 0; k0 < K; k0 += 4) {
            float4 a4[RPT];
#pragma unroll
            for (int i = 0; i < RPT; ++i)
                a4[i] = *reinterpret_cast<const float4*>(&As[g * RPT + i][k0]);
#pragma unroll
            for (int kk = 0; kk < 4; ++kk) {
                float b[JPT];
#pragma unroll
                for (int j4 = 0; j4 < JPT / 4; ++j4) {
                    float4 bv = *reinterpret_cast<const float4*>(B + (size_t)(k0 + kk) * N + jbase + j4 * 4);
                    b[j4 * 4 + 0] = bv.x; b[j4 * 4 + 1] = bv.y;
                    b[j4 * 4 + 2] = bv.z; b[j4 * 4 + 3] = bv.w;
                }
#pragma unroll
                for (int i = 0; i < RPT; ++i) {
                    float a = (kk == 0) ? a4[i].x : (kk == 1) ? a4[i].y : (kk == 2) ? a4[i].z : a4[i].w;
#pragma unroll
                    for (int j = 0; j < JPT; ++j) acc[i][j] = fmaf(a, b[j], acc[i][j]);
                }
            }
        }
    } else {
        for (int k = 0; k < K; ++k) {
            float b[JPT];
#pragma unroll
            for (int j = 0; j < JPT; ++j) b[j] = B[(size_t)k * N + jbase + j];
#pragma unroll
            for (int i = 0; i < RPT; ++i) {
                float a = As[g * RPT + i][k];
#pragma unroll
                for (int j = 0; j < JPT; ++j) acc[i][j] = fmaf(a, b[j], acc[i][j]);
            }
        }
    }

#pragma unroll
    for (int i = 0; i < RPT; ++i) {
        size_t m = m0 + g * RPT + i;
#pragma unroll
        for (int j = 0; j < JPT; ++j) {
            float v = acc[i][j];
            if constexpr (BIAS) v += bias[jbase + j];
            C[m * N + jbase + j] = v;
        }
    }
}

// ---------------- edge scatter (atomic) ----------------
// D=256: 64 lanes/edge (float4 each). D=128: 32 lanes/edge.
__global__ __launch_bounds__(256) void scatter256_kernel(const float* __restrict__ src,
                                                         const int* __restrict__ eidx,
                                                         const float* __restrict__ dinv,
                                                         float* __restrict__ agg) {
    int gid = blockIdx.x * 256 + threadIdx.x;
    int e = gid >> 6, l = gid & 63;
    int r = eidx[e], c = eidx[NE + e];
    float nrm = dinv[r] * dinv[c];
    float4 v = reinterpret_cast<const float4*>(src + (size_t)r * 256)[l];
    float* dst = agg + (size_t)c * 256 + l * 4;
    atomicAdd(dst + 0, nrm * v.x);
    atomicAdd(dst + 1, nrm * v.y);
    atomicAdd(dst + 2, nrm * v.z);
    atomicAdd(dst + 3, nrm * v.w);
}

__global__ __launch_bounds__(256) void scatter128_kernel(const float* __restrict__ src,
                                                         const int* __restrict__ eidx,
                                                         const float* __restrict__ dinv,
                                                         float* __restrict__ agg) {
    int gid = blockIdx.x * 256 + threadIdx.x;
    int e = gid >> 5, l = gid & 31;
    int r = eidx[e], c = eidx[NE + e];
    float nrm = dinv[r] * dinv[c];
    float4 v = reinterpret_cast<const float4*>(src + (size_t)r * 128)[l];
    float* dst = agg + (size_t)c * 128 + l * 4;
    atomicAdd(dst + 0, nrm * v.x);
    atomicAdd(dst + 1, nrm * v.y);
    atomicAdd(dst + 2, nrm * v.z);
    atomicAdd(dst + 3, nrm * v.w);
}

// ---------------- self-loop + bias (+relu) epilogues ----------------
__global__ __launch_bounds__(256) void finish1_kernel(float* __restrict__ agg1,   // becomes h
                                                      const float* __restrict__ xw,
                                                      const float* __restrict__ dinv,
                                                      const float* __restrict__ b1) {
    int gid = blockIdx.x * 256 + threadIdx.x;
    int v = gid >> 6, l = gid & 63;
    float di = dinv[v];
    float s = di * di;
    float4 a = reinterpret_cast<float4*>(agg1 + (size_t)v * 256)[l];
    float4 xv = reinterpret_cast<const float4*>(xw + (size_t)v * 256)[l];
    float4 bb = reinterpret_cast<const float4*>(b1)[l];
    a.x = fmaxf(fmaf(s, xv.x, a.x) + bb.x, 0.f);
    a.y = fmaxf(fmaf(s, xv.y, a.y) + bb.y, 0.f);
    a.z = fmaxf(fmaf(s, xv.z, a.z) + bb.z, 0.f);
    a.w = fmaxf(fmaf(s, xv.w, a.w) + bb.w, 0.f);
    reinterpret_cast<float4*>(agg1 + (size_t)v * 256)[l] = a;
}

__global__ __launch_bounds__(256) void finish2_kernel(const float* __restrict__ agg2,
                                                      const float* __restrict__ hw,
                                                      const float* __restrict__ dinv,
                                                      const float* __restrict__ b2,
                                                      float* __restrict__ f) {
    int gid = blockIdx.x * 256 + threadIdx.x;
    int v = gid >> 5, l = gid & 31;
    float di = dinv[v];
    float s = di * di;
    float4 a = reinterpret_cast<const float4*>(agg2 + (size_t)v * 128)[l];
    float4 xv = reinterpret_cast<const float4*>(hw + (size_t)v * 128)[l];
    float4 bb = reinterpret_cast<const float4*>(b2)[l];
    a.x = fmaf(s, xv.x, a.x) + bb.x;
    a.y = fmaf(s, xv.y, a.y) + bb.y;
    a.z = fmaf(s, xv.z, a.z) + bb.z;
    a.w = fmaf(s, xv.w, a.w) + bb.w;
    reinterpret_cast<float4*>(f + (size_t)v * 128)[l] = a;
}

// ---------------- fused edge MLP (decomposed) ----------------
// Uses U = f @ Wp1[:128,:], V = f @ Wp1[128:,:] precomputed per node.
// Per block: 32 edges. hid = relu(U[r] + V[c] + bp1) -> LDS (float4 writes);
// out = hid @ Wp2 + bp2 -> global. 256 threads, ~33 KiB LDS.
__global__ __launch_bounds__(256) void edgemlp2_kernel(const float* __restrict__ U,
                                                       const float* __restrict__ V,
                                                       const int* __restrict__ eidx,
                                                       const float* __restrict__ bp1,
                                                       const float* __restrict__ Wp2,
                                                       const float* __restrict__ bp2,
                                                       float* __restrict__ out) {
    __shared__ float hid[32][260];   // +4 pad: rotates banks across rows, b128-aligned (1040B)
    const int t = threadIdx.x;
    const int e0 = blockIdx.x * 32;

    {   // gather+add+relu: 8 threads/edge, consecutive float4s per octet (coalesced 128B)
        int le = t >> 3, sub = t & 7;
        int e = e0 + le;
        int r = eidx[e], c = eidx[NE + e];
        const float4* u4 = reinterpret_cast<const float4*>(U + (size_t)r * 256);
        const float4* v4 = reinterpret_cast<const float4*>(V + (size_t)c * 256);
        const float4* b4 = reinterpret_cast<const float4*>(bp1);
#pragma unroll
        for (int i = 0; i < 8; ++i) {
            int idx = i * 8 + sub;          // float4 index within the 256-wide row
            float4 u = u4[idx];
            float4 v = v4[idx];
            float4 b = b4[idx];
            float4 h;
            h.x = fmaxf(u.x + v.x + b.x, 0.f);
            h.y = fmaxf(u.y + v.y + b.y, 0.f);
            h.z = fmaxf(u.z + v.z + b.z, 0.f);
            h.w = fmaxf(u.w + v.w + b.w, 0.f);
            *reinterpret_cast<float4*>(&hid[le][idx * 4]) = h;
        }
    }
    __syncthreads();

    {   // GEMM2: K=256, N=128, 8 groups x 4 edges, 32 threads x 4 cols
        const int g = t >> 5;
        const int jbase = (t & 31) * 4;
        float bias2[4];
#pragma unroll
        for (int j = 0; j < 4; ++j) bias2[j] = bp2[jbase + j];
        float acc[4][4];
#pragma unroll
        for (int i = 0; i < 4; ++i)
#pragma unroll
            for (int j = 0; j < 4; ++j) acc[i][j] = 0.f;
        for (int k0 = 0; k0 < 256; k0 += 4) {
            float4 a4[4];
#pragma unroll
            for (int i = 0; i < 4; ++i)
                a4[i] = *reinterpret_cast<const float4*>(&hid[g * 4 + i][k0]);
#pragma unroll
            for (int kk = 0; kk < 4; ++kk) {
                float4 bv = *reinterpret_cast<const float4*>(Wp2 + (size_t)(k0 + kk) * 128 + jbase);
                float b[4] = {bv.x, bv.y, bv.z, bv.w};
#pragma unroll
                for (int i = 0; i < 4; ++i) {
                    float a = (kk == 0) ? a4[i].x : (kk == 1) ? a4[i].y : (kk == 2) ? a4[i].z : a4[i].w;
#pragma unroll
                    for (int j = 0; j < 4; ++j) acc[i][j] = fmaf(a, b[j], acc[i][j]);
                }
            }
        }
#pragma unroll
        for (int i = 0; i < 4; ++i) {
            float4 o;
            o.x = acc[i][0] + bias2[0];
            o.y = acc[i][1] + bias2[1];
            o.z = acc[i][2] + bias2[2];
            o.w = acc[i][3] + bias2[3];
            *reinterpret_cast<float4*>(out + (size_t)(e0 + g * 4 + i) * 128 + jbase) = o;
        }
    }
}

// ---------------- launch ----------------
extern "C" void kernel_launch(void* const* d_in, const int* in_sizes, int n_in,
                              void* d_out, int out_size, void* d_ws, size_t ws_size,
                              hipStream_t stream) {
    const float* x   = (const float*)d_in[0];
    const int*   ei  = (const int*)d_in[1];
    const float* W1  = (const float*)d_in[2];
    const float* b1  = (const float*)d_in[3];
    const float* W2  = (const float*)d_in[4];
    const float* b2  = (const float*)d_in[5];
    const float* Wp1 = (const float*)d_in[6];
    const float* bp1 = (const float*)d_in[7];
    const float* Wp2 = (const float*)d_in[8];
    const float* bp2 = (const float*)d_in[9];
    const float* Wc  = (const float*)d_in[10];
    const float* bc  = (const float*)d_in[11];
    float* out = (float*)d_out;
    float* ws  = (float*)d_ws;

    // ws layout (floats): deg[N] | agg1[N*256] | agg2[N*128] | dinv[N] | xw/hw[N*256] | eidx[2E] (int)
    // after step 9, agg1 region is reused for U and xw region for V (h/hw are dead)
    float* deg  = ws;
    float* agg1 = ws + (size_t)NN;                 // later: h (in place), then U
    float* agg2 = agg1 + (size_t)NN * 256;
    float* dinv = agg2 + (size_t)NN * 128;
    float* xw   = dinv + (size_t)NN;               // later: hw (in place region), then V
    int*   eidx = (int*)(xw + (size_t)NN * 256);

    const int n2e = 2 * NE;

    // 1. normalize edge_index dtype into int32 buffer
    convert_ei_kernel<<<(n2e + 255) / 256, 256, 0, stream>>>(ei, eidx, n2e);
    // 2. zero deg + agg1 + agg2  (385*NN floats, exact multiple of 4)
    {
        int n4 = 385 * NN / 4;
        zero_kernel<<<(n4 + 255) / 256, 256, 0, stream>>>((float4*)ws, n4);
    }
    // 3. degree + dinv
    degree_kernel<<<NE / 256, 256, 0, stream>>>(eidx, deg);
    dinv_kernel<<<(NN + 255) / 256, 256, 0, stream>>>(deg, dinv);
    // 4. xw = x @ W1
    gemm32_kernel<256, 256, 8, false, 0><<<NN / 32, 256, 0, stream>>>(x, W1, nullptr, xw);
    // 5. agg1 += norm * xw[r]  (scatter to targets)
    scatter256_kernel<<<NE * 64 / 256, 256, 0, stream>>>(xw, eidx, dinv, agg1);
    // 6. h = relu(agg1 + dinv^2*xw + b1)   (in place in agg1)
    finish1_kernel<<<NN * 64 / 256, 256, 0, stream>>>(agg1, xw, dinv, b1);
    // 7. hw = h @ W2   (into xw region)
    gemm32_kernel<256, 128, 4, false, 0><<<NN / 32, 256, 0, stream>>>(agg1, W2, nullptr, xw);
    // 8. agg2 += norm * hw[r]
    scatter128_kernel<<<NE * 32 / 256, 256, 0, stream>>>(xw, eidx, dinv, agg2);
    // 9. f = agg2 + dinv^2*hw + b2  -> d_out chunk 0
    finish2_kernel<<<NN * 32 / 256, 256, 0, stream>>>(agg2, xw, dinv, b2, out);
    // 9b. U = f @ Wp1[:128,:]   (into agg1 region — h is dead)
    gemm32_kernel<128, 256, 8, false, 0><<<NN / 32, 256, 0, stream>>>(out, Wp1, nullptr, agg1);
    // 9c. V = f @ Wp1[128:,:]   (into xw region — hw is dead)
    gemm32_kernel<128, 256, 8, false, 0><<<NN / 32, 256, 0, stream>>>(out, Wp1 + (size_t)128 * 256, nullptr, xw);
    // 10. edge MLP (decomposed) -> d_out chunk 1
    edgemlp2_kernel<<<NE / 32, 256, 0, stream>>>(agg1, xw, eidx, bp1, Wp2, bp2, out + OFF_EF);
    // 11. logits = f @ Wc + bc -> d_out chunk 2
    gemm32_kernel<128, 40, 5, true, 1><<<NN / 32, 256, 0, stream>>>(out, Wc, bc, out + OFF_LG);
    // 12. edge_index echo as float -> d_out chunk 3
    copyei_kernel<<<n2e / 256, 256, 0, stream>>>(eidx, out + OFF_EI, n2e);
}

// Round 2
// 2355.642 us; speedup vs baseline: 3.2515x; 2.6717x over previous
//
#include <hip/hip_runtime.h>

// ---------------- problem constants ----------------
#define NN 100000     // nodes
#define NE 800000     // edges
#define DIN 256
#define DHID 256
#define DOUT 128
#define DEP 256
#define NCLS 40

static constexpr size_t OFF_EF = (size_t)NN * DOUT;                 // edge_feats
static constexpr size_t OFF_LG = OFF_EF + (size_t)NE * DOUT;        // logits
static constexpr size_t OFF_EI = OFF_LG + (size_t)NN * NCLS;        // edge_index (as float)

#define SCAN_BLOCKS ((NN + 255) / 256)   // 391

// ---------------- utility kernels ----------------

// Detect int64 vs int32 edge_index layout and convert to int32 buffer.
__global__ __launch_bounds__(256) void convert_ei_kernel(const int* __restrict__ ei32,
                                                         int* __restrict__ eidx, int n2e) {
    __shared__ int is64;
    if (threadIdx.x == 0) {
        int ored = 0;
        for (int i = 0; i < 64; ++i) ored |= ei32[2 * i + 1];
        is64 = (ored == 0) ? 1 : 0;   // int64 little-endian: high words all zero
    }
    __syncthreads();
    int i = blockIdx.x * 256 + threadIdx.x;
    if (i < n2e) {
        if (is64) {
            const long long* e64 = (const long long*)ei32;
            eidx[i] = (int)e64[i];
        } else {
            eidx[i] = ei32[i];
        }
    }
}

__global__ __launch_bounds__(256) void zero_kernel(float4* __restrict__ p, int n4) {
    int i = blockIdx.x * 256 + threadIdx.x;
    if (i < n4) p[i] = make_float4(0.f, 0.f, 0.f, 0.f);
}

__global__ __launch_bounds__(256) void degree_kernel(const int* __restrict__ eidx,
                                                     int* __restrict__ deg) {
    int e = blockIdx.x * 256 + threadIdx.x;
    if (e < NE) atomicAdd(&deg[eidx[NE + e]], 1);
}

__global__ __launch_bounds__(256) void dinv_kernel(const int* __restrict__ deg,
                                                   float* __restrict__ dinv) {
    int v = blockIdx.x * 256 + threadIdx.x;
    if (v < NN) dinv[v] = rsqrtf((float)deg[v] + 1.0f);   // +1 self-loop; deg>=1 always
}

__global__ __launch_bounds__(256) void copyei_kernel(const int* __restrict__ eidx,
                                                     float* __restrict__ out, int n2e) {
    int i = blockIdx.x * 256 + threadIdx.x;
    if (i < n2e) out[i] = (float)eidx[i];
}

// ---------------- CSR build: block sums -> scan block sums -> final scan -> bucket ----------------
__global__ __launch_bounds__(256) void blocksum_kernel(const int* __restrict__ deg,
                                                       int* __restrict__ bsum) {
    __shared__ int red[256];
    int t = threadIdx.x;
    int v = blockIdx.x * 256 + t;
    red[t] = (v < NN) ? deg[v] : 0;
    __syncthreads();
    for (int off = 128; off > 0; off >>= 1) {
        if (t < off) red[t] += red[t + off];
        __syncthreads();
    }
    if (t == 0) bsum[blockIdx.x] = red[0];
}

__global__ __launch_bounds__(256) void scanbsum_kernel(int* __restrict__ bsum, int nb) {
    // single-block exclusive scan over nb elements (in place)
    __shared__ int buf[256];
    __shared__ int base;
    int t = threadIdx.x;
    if (t == 0) base = 0;
    __syncthreads();
    for (int start = 0; start < nb; start += 256) {
        int i = start + t;
        int d = (i < nb) ? bsum[i] : 0;
        int val = d;
        buf[t] = val;
        __syncthreads();
        for (int off = 1; off < 256; off <<= 1) {
            int add = (t >= off) ? buf[t - off] : 0;
            __syncthreads();
            val += add;
            buf[t] = val;
            __syncthreads();
        }
        int total = buf[255];
        if (i < nb) bsum[i] = base + val - d;   // exclusive
        __syncthreads();
        if (t == 0) base += total;
        __syncthreads();
    }
}

__global__ __launch_bounds__(256) void scanfinal_kernel(const int* __restrict__ deg,
                                                        const int* __restrict__ bsum,
                                                        int* __restrict__ rowptr) {
    __shared__ int buf[256];
    int t = threadIdx.x;
    int v = blockIdx.x * 256 + t;
    int d = (v < NN) ? deg[v] : 0;
    int val = d;
    buf[t] = val;
    __syncthreads();
    for (int off = 1; off < 256; off <<= 1) {
        int add = (t >= off) ? buf[t - off] : 0;
        __syncthreads();
        val += add;
        buf[t] = val;
        __syncthreads();
    }
    if (v < NN) rowptr[v + 1] = bsum[blockIdx.x] + val;   // inclusive within block + base
    if (blockIdx.x == 0 && t == 0) rowptr[0] = 0;
}

__global__ __launch_bounds__(256) void bucket_kernel(const int* __restrict__ eidx,
                                                     const int* __restrict__ rowptr,
                                                     int* __restrict__ fill,
                                                     int* __restrict__ ebuf) {
    int e = blockIdx.x * 256 + threadIdx.x;
    if (e < NE) {
        int c = eidx[NE + e];
        int pos = atomicAdd(&fill[c], 1);
        ebuf[rowptr[c] + pos] = eidx[e];   // store source node r
    }
}

// ---------------- gather-style aggregation (CSR), fused self-loop+bias(+relu) ----------------
// One wave (64 lanes) per destination node. D=256: float4/lane. D=128: float2/lane.
__global__ __launch_bounds__(256) void agg256_kernel(const float* __restrict__ xw,
                                                     const int* __restrict__ rowptr,
                                                     const int* __restrict__ ebuf,
                                                     const float* __restrict__ dinv,
                                                     const float* __restrict__ b1,
                                                     float* __restrict__ h) {
    int gid = blockIdx.x * 256 + threadIdx.x;
    int v = gid >> 6, l = gid & 63;
    int p0 = rowptr[v], p1 = rowptr[v + 1];
    float dc = dinv[v];
    float4 acc;
    {   // self-loop: dinv[v]^2 * xw[v]
        float s = dc * dc;
        float4 xv = reinterpret_cast<const float4*>(xw + (size_t)v * 256)[l];
        acc.x = s * xv.x; acc.y = s * xv.y; acc.z = s * xv.z; acc.w = s * xv.w;
    }
    int r = 0; float dr = 0.f;
    if (p0 < p1) { r = ebuf[p0]; dr = dinv[r]; }
    for (int p = p0; p < p1;) {
        float nrm = dc * dr;
        float4 xv = reinterpret_cast<const float4*>(xw + (size_t)r * 256)[l];
        ++p;
        if (p < p1) { r = ebuf[p]; dr = dinv[r]; }   // prefetch next edge scalars
        acc.x = fmaf(nrm, xv.x, acc.x);
        acc.y = fmaf(nrm, xv.y, acc.y);
        acc.z = fmaf(nrm, xv.z, acc.z);
        acc.w = fmaf(nrm, xv.w, acc.w);
    }
    float4 bb = reinterpret_cast<const float4*>(b1)[l];
    acc.x = fmaxf(acc.x + bb.x, 0.f);
    acc.y = fmaxf(acc.y + bb.y, 0.f);
    acc.z = fmaxf(acc.z + bb.z, 0.f);
    acc.w = fmaxf(acc.w + bb.w, 0.f);
    reinterpret_cast<float4*>(h + (size_t)v * 256)[l] = acc;
}

__global__ __launch_bounds__(256) void agg128_kernel(const float* __restrict__ hw,
                                                     const int* __restrict__ rowptr,
                                                     const int* __restrict__ ebuf,
                                                     const float* __restrict__ dinv,
                                                     const float* __restrict__ b2,
                                                     float* __restrict__ f) {
    int gid = blockIdx.x * 256 + threadIdx.x;
    int v = gid >> 6, l = gid & 63;
    int p0 = rowptr[v], p1 = rowptr[v + 1];
    float dc = dinv[v];
    float2 acc;
    {
        float s = dc * dc;
        float2 xv = reinterpret_cast<const float2*>(hw + (size_t)v * 128)[l];
        acc.x = s * xv.x; acc.y = s * xv.y;
    }
    int r = 0; float dr = 0.f;
    if (p0 < p1) { r = ebuf[p0]; dr = dinv[r]; }
    for (int p = p0; p < p1;) {
        float nrm = dc * dr;
        float2 xv = reinterpret_cast<const float2*>(hw + (size_t)r * 128)[l];
        ++p;
        if (p < p1) { r = ebuf[p]; dr = dinv[r]; }
        acc.x = fmaf(nrm, xv.x, acc.x);
        acc.y = fmaf(nrm, xv.y, acc.y);
    }
    float2 bb = reinterpret_cast<const float2*>(b2)[l];
    acc.x += bb.x; acc.y += bb.y;
    reinterpret_cast<float2*>(f + (size_t)v * 128)[l] = acc;
}

// ---------------- generic 32-row GEMM: C[M,N] = A[M,K] @ B[K,N] (+bias) ----------------
// 256 threads, TM=32 rows/block. K,N <= 256. JPT cols per thread.
template <int K, int N, int JPT, bool BIAS, int PAD>
__global__ __launch_bounds__(256) void gemm32_kernel(const float* __restrict__ A,
                                                     const float* __restrict__ B,
                                                     const float* __restrict__ bias,
                                                     float* __restrict__ C) {
    constexpr int TPR = N / JPT;       // threads covering one row's N cols
    constexpr int GROUPS = 256 / TPR;  // row groups
    constexpr int RPT = 32 / GROUPS;   // rows per thread
    __shared__ float As[32][K + PAD];

    const int t = threadIdx.x;
    const size_t m0 = (size_t)blockIdx.x * 32;

    // stage A tile (M is an exact multiple of 32 for all uses)
    for (int idx4 = t; idx4 < 32 * K / 4; idx4 += 256) {
        int idx = idx4 * 4;
        int r = idx / K, cc = idx % K;
        float4 v = *reinterpret_cast<const float4*>(A + (m0 + r) * K + cc);
        As[r][cc + 0] = v.x; As[r][cc + 1] = v.y;
        As[r][cc + 2] = v.z; As[r][cc + 3] = v.w;
    }
    __syncthreads();

    const int g = t / TPR;
    const int jbase = (t % TPR) * JPT;

    float acc[RPT][JPT];
#pragma unroll
    for (int i = 0; i < RPT; ++i)
#pragma unroll
        for (int j = 0; j < JPT; ++j) acc[i][j] = 0.f;

    if constexpr ((JPT % 4) == 0 && PAD == 0) {
        for (int k0 = 0; k0 < K; k0 += 4) {
            float4 a4[RPT];
#pragma unroll
            for (int i = 0; i < RPT; ++i)
                a4[i] = *reinterpret_cast<const float4*>(&As[g * RPT + i][k0]);
#pragma unroll
            for (int kk = 0; kk < 4; ++kk) {
                float b[JPT];
#pragma unroll
                for (int j4 = 0; j4 < JPT / 4; ++j4) {
                    float4 bv = *reinterpret_cast<const float4*>(B + (size_t)(k0 + kk) * N + jbase + j4 * 4);
                    b[j4 * 4 + 0] = bv.x; b[j4 * 4 + 1] = bv.y;
                    b[j4 * 4 + 2] = bv.z; b[j4 * 4 + 3] = bv.w;
                }
#pragma unroll
                for (int i = 0; i < RPT; ++i) {
                    float a = (kk == 0) ? a4[i].x : (kk == 1) ? a4[i].y : (kk == 2) ? a4[i].z : a4[i].w;
#pragma unroll
                    for (int j = 0; j < JPT; ++j) acc[i][j] = fmaf(a, b[j], acc[i][j]);
                }
            }
        }
    } else {
        for (int k = 0; k < K; ++k) {
            float b[JPT];
#pragma unroll
            for (int j = 0; j < JPT; ++j) b[j] = B[(size_t)k * N + jbase + j];
#pragma unroll
            for (int i = 0; i < RPT; ++i) {
                float a = As[g * RPT + i][k];
#pragma unroll
                for (int j = 0; j < JPT; ++j) acc[i][j] = fmaf(a, b[j], acc[i][j]);
            }
        }
    }

#pragma unroll
    for (int i = 0; i < RPT; ++i) {
        size_t m = m0 + g * RPT + i;
#pragma unroll
        for (int j = 0; j < JPT; ++j) {
            float v = acc[i][j];
            if constexpr (BIAS) v += bias[jbase + j];
            C[m * N + jbase + j] = v;
        }
    }
}

// ---------------- fused edge MLP (decomposed) ----------------
// Uses U = f @ Wp1[:128,:], V = f @ Wp1[128:,:] precomputed per node.
// Per block: 32 edges. hid = relu(U[r] + V[c] + bp1) -> LDS (float4 writes);
// out = hid @ Wp2 + bp2 -> global. 256 threads, ~33 KiB LDS.
__global__ __launch_bounds__(256) void edgemlp2_kernel(const float* __restrict__ U,
                                                       const float* __restrict__ V,
                                                       const int* __restrict__ eidx,
                                                       const float* __restrict__ bp1,
                                                       const float* __restrict__ Wp2,
                                                       const float* __restrict__ bp2,
                                                       float* __restrict__ out) {
    __shared__ float hid[32][260];   // +4 pad: rotates banks across rows, b128-aligned
    const int t = threadIdx.x;
    const int e0 = blockIdx.x * 32;

    {   // gather+add+relu: 8 threads/edge, coalesced float4s
        int le = t >> 3, sub = t & 7;
        int e = e0 + le;
        int r = eidx[e], c = eidx[NE + e];
        const float4* u4 = reinterpret_cast<const float4*>(U + (size_t)r * 256);
        const float4* v4 = reinterpret_cast<const float4*>(V + (size_t)c * 256);
        const float4* b4 = reinterpret_cast<const float4*>(bp1);
#pragma unroll
        for (int i = 0; i < 8; ++i) {
            int idx = i * 8 + sub;          // float4 index within the 256-wide row
            float4 u = u4[idx];
            float4 v = v4[idx];
            float4 b = b4[idx];
            float4 h;
            h.x = fmaxf(u.x + v.x + b.x, 0.f);
            h.y = fmaxf(u.y + v.y + b.y, 0.f);
            h.z = fmaxf(u.z + v.z + b.z, 0.f);
            h.w = fmaxf(u.w + v.w + b.w, 0.f);
            *reinterpret_cast<float4*>(&hid[le][idx * 4]) = h;
        }
    }
    __syncthreads();

    {   // GEMM2: K=256, N=128, 8 groups x 4 edges, 32 threads x 4 cols
        const int g = t >> 5;
        const int jbase = (t & 31) * 4;
        float bias2[4];
#pragma unroll
        for (int j = 0; j < 4; ++j) bias2[j] = bp2[jbase + j];
        float acc[4][4];
#pragma unroll
        for (int i = 0; i < 4; ++i)
#pragma unroll
            for (int j = 0; j < 4; ++j) acc[i][j] = 0.f;
        for (int k0 = 0; k0 < 256; k0 += 4) {
            float4 a4[4];
#pragma unroll
            for (int i = 0; i < 4; ++i)
                a4[i] = *reinterpret_cast<const float4*>(&hid[g * 4 + i][k0]);
#pragma unroll
            for (int kk = 0; kk < 4; ++kk) {
                float4 bv = *reinterpret_cast<const float4*>(Wp2 + (size_t)(k0 + kk) * 128 + jbase);
                float b[4] = {bv.x, bv.y, bv.z, bv.w};
#pragma unroll
                for (int i = 0; i < 4; ++i) {
                    float a = (kk == 0) ? a4[i].x : (kk == 1) ? a4[i].y : (kk == 2) ? a4[i].z : a4[i].w;
#pragma unroll
                    for (int j = 0; j < 4; ++j) acc[i][j] = fmaf(a, b[j], acc[i][j]);
                }
            }
        }
#pragma unroll
        for (int i = 0; i < 4; ++i) {
            float4 o;
            o.x = acc[i][0] + bias2[0];
            o.y = acc[i][1] + bias2[1];
            o.z = acc[i][2] + bias2[2];
            o.w = acc[i][3] + bias2[3];
            *reinterpret_cast<float4*>(out + (size_t)(e0 + g * 4 + i) * 128 + jbase) = o;
        }
    }
}

// ---------------- launch ----------------
extern "C" void kernel_launch(void* const* d_in, const int* in_sizes, int n_in,
                              void* d_out, int out_size, void* d_ws, size_t ws_size,
                              hipStream_t stream) {
    const float* x   = (const float*)d_in[0];
    const int*   ei  = (const int*)d_in[1];
    const float* W1  = (const float*)d_in[2];
    const float* b1  = (const float*)d_in[3];
    const float* W2  = (const float*)d_in[4];
    const float* b2  = (const float*)d_in[5];
    const float* Wp1 = (const float*)d_in[6];
    const float* bp1 = (const float*)d_in[7];
    const float* Wp2 = (const float*)d_in[8];
    const float* bp2 = (const float*)d_in[9];
    const float* Wc  = (const float*)d_in[10];
    const float* bc  = (const float*)d_in[11];
    float* out = (float*)d_out;
    float* ws  = (float*)d_ws;

    // ws layout (floats):
    //   A[NN*256]  : xw -> (first half) hw -> U
    //   B[NN*256]  : h -> V
    //   dinv[NN]
    //   ints: deg[NN] (later fill-reuse? kept separate) | fill[NN] | rowptr[NN+1] | bsum[512] | ebuf[NE] | eidx[2*NE]
    float* A    = ws;
    float* B    = A + (size_t)NN * 256;
    float* dinv = B + (size_t)NN * 256;
    int*   ints   = (int*)(dinv + NN);
    int*   deg    = ints;
    int*   fill   = ints + NN;
    int*   rowptr = ints + 2 * NN;
    int*   bsum   = ints + 3 * NN + 1;
    int*   ebuf   = bsum + 512;
    int*   eidx   = ebuf + NE;

    const int n2e = 2 * NE;

    // 1. normalize edge_index dtype into int32 buffer
    convert_ei_kernel<<<(n2e + 255) / 256, 256, 0, stream>>>(ei, eidx, n2e);
    // 2. zero deg + fill (2*NN ints = 50000 float4, 16B-aligned)
    zero_kernel<<<(50000 + 255) / 256, 256, 0, stream>>>((float4*)deg, 50000);
    // 3. degree + dinv
    degree_kernel<<<NE / 256, 256, 0, stream>>>(eidx, deg);
    dinv_kernel<<<(NN + 255) / 256, 256, 0, stream>>>(deg, dinv);
    // 4. CSR: rowptr = exclusive-scan(deg), bucket edge sources by target
    blocksum_kernel<<<SCAN_BLOCKS, 256, 0, stream>>>(deg, bsum);
    scanbsum_kernel<<<1, 256, 0, stream>>>(bsum, SCAN_BLOCKS);
    scanfinal_kernel<<<SCAN_BLOCKS, 256, 0, stream>>>(deg, bsum, rowptr);
    bucket_kernel<<<NE / 256, 256, 0, stream>>>(eidx, rowptr, fill, ebuf);
    // 5. xw = x @ W1 -> A
    gemm32_kernel<256, 256, 8, false, 0><<<NN / 32, 256, 0, stream>>>(x, W1, nullptr, A);
    // 6. h = relu(agg(xw) + dinv^2*xw + b1) -> B   (gather CSR, fused epilogue)
    agg256_kernel<<<NN * 64 / 256, 256, 0, stream>>>(A, rowptr, ebuf, dinv, b1, B);
    // 7. hw = h @ W2 -> A (first NN*128 region; xw dead)
    gemm32_kernel<256, 128, 4, false, 0><<<NN / 32, 256, 0, stream>>>(B, W2, nullptr, A);
    // 8. f = agg(hw) + dinv^2*hw + b2 -> d_out chunk 0   (gather CSR, fused epilogue)
    agg128_kernel<<<NN * 64 / 256, 256, 0, stream>>>(A, rowptr, ebuf, dinv, b2, out);
    // 9. U = f @ Wp1[:128,:] -> A (hw dead)
    gemm32_kernel<128, 256, 8, false, 0><<<NN / 32, 256, 0, stream>>>(out, Wp1, nullptr, A);
    // 10. V = f @ Wp1[128:,:] -> B (h dead)
    gemm32_kernel<128, 256, 8, false, 0><<<NN / 32, 256, 0, stream>>>(out, Wp1 + (size_t)128 * 256, nullptr, B);
    // 11. edge MLP (decomposed) -> d_out chunk 1
    edgemlp2_kernel<<<NE / 32, 256, 0, stream>>>(A, B, eidx, bp1, Wp2, bp2, out + OFF_EF);
    // 12. logits = f @ Wc + bc -> d_out chunk 2
    gemm32_kernel<128, 40, 5, true, 1><<<NN / 32, 256, 0, stream>>>(out, Wc, bc, out + OFF_LG);
    // 13. edge_index echo as float -> d_out chunk 3
    copyei_kernel<<<n2e / 256, 256, 0, stream>>>(eidx, out + OFF_EI, n2e);
}